// Round 2
// baseline (765.065 us; speedup 1.0000x reference)
//
#include <hip/hip_runtime.h>

// PulseFloatingPointEncoder: per element emit 8 fp32 flags
// [sign, e3, e2, e1, e0, m2, m1, m0] of a truncated e4m3-style encoding.
// E_BITS=4, M_BITS=3, N_INT=10, N_DEC=10, BIAS=7, START_EXP=17, SUB_START=16.
//
// R1 lesson: one thread per element => two stride-32B dwordx4 stores per wave
// => partial-line/partial-sector HBM writes => ~1 TB/s (6x off roofline).
// R2: two threads per element, each stores exactly one contiguous float4.

__device__ __forceinline__ void encode_one(float x, float4& lo, float4& hi) {
    float sign = (x < 0.0f) ? 1.0f : 0.0f;   // note: -0.0f -> 0 (matches ref x<0)
    unsigned ub = __float_as_uint(x) & 0x7fffffffu;
    float a = __uint_as_float(ub);
    int e_lead = (int)(ub >> 23) - 127;      // floor(log2 a) for normals; <=-127 for subnorm/zero

    int ec, mant;
    if (__builtin_expect(e_lead >= 10, 0)) {
        // a >= 1024 (or inf/nan): faithful emulation of the reference greedy scan.
        float V = a;
        int has_fired = 0, d0 = 0, d1 = 0, d2 = 0;
        int e_reg = 0, m0 = 0, m1 = 0, m2 = 0;
        for (int t = 0; t < 20; ++t) {
            float thr = __builtin_exp2f((float)(9 - t));   // exact powers of two
            int s = (V >= thr) ? 1 : 0;
            if (s) V -= thr;                                // exact: V - s*thr
            int fs = s & (has_fired ^ 1);
            int active = (t < 16) ? 1 : 0;
            int counter = (16 - t) > 0 ? (16 - t) : 0;
            if (fs & active) e_reg |= (counter & 15);
            if (s) { m0 |= d0; m1 |= d1; m2 |= d2; }
            int vfs = fs & active;
            d2 = d1; d1 = d0; d0 = vfs;
            has_fired |= vfs;
            if (t >= 16 && t <= 18) {
                int bit = s & (has_fired ^ 1);
                if (t == 16) m0 |= bit; else if (t == 17) m1 |= bit; else m2 |= bit;
            }
        }
        ec = e_reg;
        mant = (m0 << 2) | (m1 << 1) | m2;
    } else {
        bool norm = (e_lead >= -6);
        bool sub  = (e_lead >= -10) & !norm;
        // normal: exponent code (7+e_lead)&15, mantissa = top 3 fraction bits (truncate)
        int ec_n   = (7 + e_lead) & 15;
        int mant_n = (int)(ub >> 20) & 7;
        // subnormal range [2^-10, 2^-6): bits at weights 2^-7..2^-9
        int mant_s = ((int)(a * 512.0f)) & 7;   // a*512 in [0.5, 8), exact scaling, trunc
        ec   = norm ? ec_n : 0;
        mant = norm ? mant_n : (sub ? mant_s : 0);
    }

    lo.x = sign;
    lo.y = (float)((ec >> 3) & 1);   // e_out is e_reg reversed => MSB first
    lo.z = (float)((ec >> 2) & 1);
    lo.w = (float)((ec >> 1) & 1);
    hi.x = (float)(ec & 1);
    hi.y = (float)((mant >> 2) & 1); // m_reg[0] = most significant mantissa bit
    hi.z = (float)((mant >> 1) & 1);
    hi.w = (float)(mant & 1);
}

// One thread per OUTPUT float4 (two threads per input element).
// Lane j stores 16B at byte offset 16*j: wave store = 1KB dense contiguous.
__global__ __launch_bounds__(256) void pulse_encode_kernel(
        const float* __restrict__ in, float4* __restrict__ out, int n2) {
    int j = blockIdx.x * 256 + threadIdx.x;
    if (j >= n2) return;
    int i = j >> 1;
    float x = in[i];
    float4 lo, hi;
    encode_one(x, lo, hi);
    out[j] = (j & 1) ? hi : lo;
}

extern "C" void kernel_launch(void* const* d_in, const int* in_sizes, int n_in,
                              void* d_out, int out_size, void* d_ws, size_t ws_size,
                              hipStream_t stream) {
    const float* x = (const float*)d_in[0];
    float4* out = (float4*)d_out;
    int n = in_sizes[0];                  // 8*2048*1024 = 16,777,216
    int n2 = 2 * n;                       // number of output float4s
    int blocks = (n2 + 255) / 256;
    pulse_encode_kernel<<<blocks, 256, 0, stream>>>(x, out, n2);
}

// Round 3
// 720.675 us; speedup vs baseline: 1.0616x; 1.0616x over previous
//
#include <hip/hip_runtime.h>

// PulseFloatingPointEncoder: per element emit 8 fp32 flags
// [sign, e3, e2, e1, e0, m2, m1, m0] of a truncated e4m3-style encoding.
// E_BITS=4, M_BITS=3, N_INT=10, N_DEC=10, BIAS=7, START_EXP=17, SUB_START=16.
//
// R1: 1 thread/element, dword load, 2x dwordx4 stores (32B/thread) -> kernel ~230us.
// R2: 2 threads/element, dense per-instr stores, broadcast loads    -> kernel ~395us.
//     => per-instruction store density is NOT the limiter; wave count / per-wave
//        memory parallelism is. R3: 4 elements/thread, float4 loads, 4x fewer waves.

__device__ __forceinline__ void encode_one(float x, float4& lo, float4& hi) {
    float sign = (x < 0.0f) ? 1.0f : 0.0f;   // note: -0.0f -> 0 (matches ref x<0)
    unsigned ub = __float_as_uint(x) & 0x7fffffffu;
    float a = __uint_as_float(ub);
    int e_lead = (int)(ub >> 23) - 127;      // floor(log2 a) for normals; <=-127 for subnorm/zero

    int ec, mant;
    if (__builtin_expect(e_lead >= 10, 0)) {
        // a >= 1024 (or inf/nan): faithful emulation of the reference greedy scan.
        float V = a;
        int has_fired = 0, d0 = 0, d1 = 0, d2 = 0;
        int e_reg = 0, m0 = 0, m1 = 0, m2 = 0;
        for (int t = 0; t < 20; ++t) {
            float thr = __builtin_exp2f((float)(9 - t));   // exact powers of two
            int s = (V >= thr) ? 1 : 0;
            if (s) V -= thr;                                // exact: V - s*thr
            int fs = s & (has_fired ^ 1);
            int active = (t < 16) ? 1 : 0;
            int counter = (16 - t) > 0 ? (16 - t) : 0;
            if (fs & active) e_reg |= (counter & 15);
            if (s) { m0 |= d0; m1 |= d1; m2 |= d2; }
            int vfs = fs & active;
            d2 = d1; d1 = d0; d0 = vfs;
            has_fired |= vfs;
            if (t >= 16 && t <= 18) {
                int bit = s & (has_fired ^ 1);
                if (t == 16) m0 |= bit; else if (t == 17) m1 |= bit; else m2 |= bit;
            }
        }
        ec = e_reg;
        mant = (m0 << 2) | (m1 << 1) | m2;
    } else {
        bool norm = (e_lead >= -6);
        bool sub  = (e_lead >= -10) & !norm;
        // normal: exponent code (7+e_lead)&15, mantissa = top 3 fraction bits (truncate)
        int ec_n   = (7 + e_lead) & 15;
        int mant_n = (int)(ub >> 20) & 7;
        // subnormal range [2^-10, 2^-6): bits at weights 2^-7..2^-9
        int mant_s = ((int)(a * 512.0f)) & 7;   // a*512 in [0.5, 8), exact scaling, trunc
        ec   = norm ? ec_n : 0;
        mant = norm ? mant_n : (sub ? mant_s : 0);
    }

    lo.x = sign;
    lo.y = (float)((ec >> 3) & 1);   // e_out is e_reg reversed => MSB first
    lo.z = (float)((ec >> 2) & 1);
    lo.w = (float)((ec >> 1) & 1);
    hi.x = (float)(ec & 1);
    hi.y = (float)((mant >> 2) & 1); // m_reg[0] = most significant mantissa bit
    hi.z = (float)((mant >> 1) & 1);
    hi.w = (float)(mant & 1);
}

// One thread per 4 input elements: one float4 load (1 KiB dense per wave load
// instruction), 8 dwordx4 stores covering 128 contiguous bytes per thread.
__global__ __launch_bounds__(256) void pulse_encode_kernel(
        const float4* __restrict__ in4, float4* __restrict__ out4, int n4) {
    int i = blockIdx.x * 256 + threadIdx.x;
    if (i >= n4) return;
    float4 v = in4[i];
    long base = (long)i * 8;
    float4 lo, hi;
    encode_one(v.x, lo, hi);
    out4[base + 0] = lo; out4[base + 1] = hi;
    encode_one(v.y, lo, hi);
    out4[base + 2] = lo; out4[base + 3] = hi;
    encode_one(v.z, lo, hi);
    out4[base + 4] = lo; out4[base + 5] = hi;
    encode_one(v.w, lo, hi);
    out4[base + 6] = lo; out4[base + 7] = hi;
}

extern "C" void kernel_launch(void* const* d_in, const int* in_sizes, int n_in,
                              void* d_out, int out_size, void* d_ws, size_t ws_size,
                              hipStream_t stream) {
    const float4* x4 = (const float4*)d_in[0];
    float4* out = (float4*)d_out;
    int n = in_sizes[0];                  // 8*2048*1024 = 16,777,216 (divisible by 4)
    int n4 = n >> 2;                      // 4,194,304 threads
    int blocks = (n4 + 255) / 256;        // 16384 blocks
    pulse_encode_kernel<<<blocks, 256, 0, stream>>>(x4, out, n4);
}

// Round 4
// 675.882 us; speedup vs baseline: 1.1320x; 1.0663x over previous
//
#include <hip/hip_runtime.h>

// PulseFloatingPointEncoder: per element emit 8 fp32 flags
// [sign, e3, e2, e1, e0, m2, m1, m0] of a truncated e4m3-style encoding.
// E_BITS=4, M_BITS=3, N_INT=10, N_DEC=10, BIAS=7, START_EXP=17, SUB_START=16.
//
// Kernel-only times (reported dur_us minus ~400us fixed harness overhead):
// R1: dword load, stride-32B stores            -> ~190us
// R2: broadcast loads, dense stores, 2x waves  -> ~360us
// R3: float4 loads, stride-128B stores         -> ~320us
// Evidence: harness fillBuffer (dense per-lane dwordx4) = 6.24 TB/s, FETCH~0.
// => dense-per-instruction stores are the ceiling pattern; R2's regression was
//    its thin waves + broadcast global loads, not the store shape.
// R4: dense float4 loads + LDS input staging + dense-per-instruction stores.
//     Each element encoded by 2 lanes (compute is ~5% busy - free).

__device__ __forceinline__ void encode_one(float x, float4& lo, float4& hi) {
    float sign = (x < 0.0f) ? 1.0f : 0.0f;   // note: -0.0f -> 0 (matches ref x<0)
    unsigned ub = __float_as_uint(x) & 0x7fffffffu;
    float a = __uint_as_float(ub);
    int e_lead = (int)(ub >> 23) - 127;      // floor(log2 a) for normals; <=-127 for subnorm/zero

    int ec, mant;
    if (__builtin_expect(e_lead >= 10, 0)) {
        // a >= 1024 (or inf/nan): faithful emulation of the reference greedy scan.
        float V = a;
        int has_fired = 0, d0 = 0, d1 = 0, d2 = 0;
        int e_reg = 0, m0 = 0, m1 = 0, m2 = 0;
        for (int t = 0; t < 20; ++t) {
            float thr = __builtin_exp2f((float)(9 - t));   // exact powers of two
            int s = (V >= thr) ? 1 : 0;
            if (s) V -= thr;                                // exact: V - s*thr
            int fs = s & (has_fired ^ 1);
            int active = (t < 16) ? 1 : 0;
            int counter = (16 - t) > 0 ? (16 - t) : 0;
            if (fs & active) e_reg |= (counter & 15);
            if (s) { m0 |= d0; m1 |= d1; m2 |= d2; }
            int vfs = fs & active;
            d2 = d1; d1 = d0; d0 = vfs;
            has_fired |= vfs;
            if (t >= 16 && t <= 18) {
                int bit = s & (has_fired ^ 1);
                if (t == 16) m0 |= bit; else if (t == 17) m1 |= bit; else m2 |= bit;
            }
        }
        ec = e_reg;
        mant = (m0 << 2) | (m1 << 1) | m2;
    } else {
        bool norm = (e_lead >= -6);
        bool sub  = (e_lead >= -10) & !norm;
        // normal: exponent code (7+e_lead)&15, mantissa = top 3 fraction bits (truncate)
        int ec_n   = (7 + e_lead) & 15;
        int mant_n = (int)(ub >> 20) & 7;
        // subnormal range [2^-10, 2^-6): bits at weights 2^-7..2^-9
        int mant_s = ((int)(a * 512.0f)) & 7;   // a*512 in [0.5, 8), exact scaling, trunc
        ec   = norm ? ec_n : 0;
        mant = norm ? mant_n : (sub ? mant_s : 0);
    }

    lo.x = sign;
    lo.y = (float)((ec >> 3) & 1);   // e_out is e_reg reversed => MSB first
    lo.z = (float)((ec >> 2) & 1);
    lo.w = (float)((ec >> 1) & 1);
    hi.x = (float)(ec & 1);
    hi.y = (float)((mant >> 2) & 1); // m_reg[0] = most significant mantissa bit
    hi.z = (float)((mant >> 1) & 1);
    hi.w = (float)(mant & 1);
}

// Block = 256 threads, 1024 input elements, 2048 output float4s.
// Phase 1: dense float4 load -> LDS (4KB).
// Phase 2: store instr k: thread t writes out4[base + k*256 + t] (fully dense
//          per instruction, 4KB/block/instr). Needed element = k*128 + (t>>1),
//          read from LDS (32 consecutive dwords/wave, pairs broadcast: no
//          bank conflicts). Half select = t&1.
__global__ __launch_bounds__(256) void pulse_encode_kernel(
        const float4* __restrict__ in4, float4* __restrict__ out4) {
    __shared__ float xs[1024];
    const int t = threadIdx.x;
    const long blk = blockIdx.x;

    ((float4*)xs)[t] = in4[blk * 256 + t];
    __syncthreads();

    const long out_base = blk * 2048;
    #pragma unroll
    for (int k = 0; k < 8; ++k) {
        const int g = k * 256 + t;           // out float4 index within block
        const float x = xs[g >> 1];          // element index within block
        float4 lo, hi;
        encode_one(x, lo, hi);
        out4[out_base + g] = (t & 1) ? hi : lo;
    }
}

extern "C" void kernel_launch(void* const* d_in, const int* in_sizes, int n_in,
                              void* d_out, int out_size, void* d_ws, size_t ws_size,
                              hipStream_t stream) {
    const float4* x4 = (const float4*)d_in[0];
    float4* out = (float4*)d_out;
    int n = in_sizes[0];                  // 8*2048*1024 = 16,777,216 (divisible by 1024)
    int blocks = n / 1024;                // 16384 blocks
    pulse_encode_kernel<<<blocks, 256, 0, stream>>>(x4, out);
}

// Round 6
// 653.071 us; speedup vs baseline: 1.1715x; 1.0349x over previous
//
#include <hip/hip_runtime.h>

// PulseFloatingPointEncoder: per element emit 8 fp32 flags
// [sign, e3, e2, e1, e0, m2, m1, m0] of a truncated e4m3-style encoding.
// E_BITS=4, M_BITS=3, N_INT=10, N_DEC=10, BIAS=7, START_EXP=17, SUB_START=16.
//
// Measured ladder (reported dur_us; ~430us of harness fill/restore rides along):
// R1 597: 1 thr/elem, dword load, 2x dwordx4 stores (stride-32B)   <- best
// R2 765: 2 thr/elem, dense stores, broadcast loads (2x waves+VALU) = 2x R1
// R3 720: 4 elem/thr, float4 load, 8 stores/thr (stride-128B)
// R4 676: LDS-staged, dense-per-instr stores, 2x VALU
// => not HBM-bound at this point: R2's 2x waves/VALU doubled time while all
//    kernels issue identical total store instructions. Bound per-wave.
// R5: R1's exact load/store shape, but 4 grid-strided elements per thread:
//    4 independent loads batched (MLP=4), 4x fewer waves, same VALU/element,
//    no LDS/barrier. Nontemporal loads/stores (write-once / read-once data).
// R5b: use clang ext_vector_type for nontemporal builtins (HIP_vector_type
//    is rejected by __builtin_nontemporal_store).

typedef float f32x4 __attribute__((ext_vector_type(4)));

__device__ __forceinline__ void encode_one(float x, f32x4& lo, f32x4& hi) {
    float sign = (x < 0.0f) ? 1.0f : 0.0f;   // note: -0.0f -> 0 (matches ref x<0)
    unsigned ub = __float_as_uint(x) & 0x7fffffffu;
    float a = __uint_as_float(ub);
    int e_lead = (int)(ub >> 23) - 127;      // floor(log2 a) for normals; <=-127 for subnorm/zero

    int ec, mant;
    if (__builtin_expect(e_lead >= 10, 0)) {
        // a >= 1024 (or inf/nan): faithful emulation of the reference greedy scan.
        float V = a;
        int has_fired = 0, d0 = 0, d1 = 0, d2 = 0;
        int e_reg = 0, m0 = 0, m1 = 0, m2 = 0;
        for (int t = 0; t < 20; ++t) {
            float thr = __builtin_exp2f((float)(9 - t));   // exact powers of two
            int s = (V >= thr) ? 1 : 0;
            if (s) V -= thr;                                // exact: V - s*thr
            int fs = s & (has_fired ^ 1);
            int active = (t < 16) ? 1 : 0;
            int counter = (16 - t) > 0 ? (16 - t) : 0;
            if (fs & active) e_reg |= (counter & 15);
            if (s) { m0 |= d0; m1 |= d1; m2 |= d2; }
            int vfs = fs & active;
            d2 = d1; d1 = d0; d0 = vfs;
            has_fired |= vfs;
            if (t >= 16 && t <= 18) {
                int bit = s & (has_fired ^ 1);
                if (t == 16) m0 |= bit; else if (t == 17) m1 |= bit; else m2 |= bit;
            }
        }
        ec = e_reg;
        mant = (m0 << 2) | (m1 << 1) | m2;
    } else {
        bool norm = (e_lead >= -6);
        bool sub  = (e_lead >= -10) & !norm;
        // normal: exponent code (7+e_lead)&15, mantissa = top 3 fraction bits (truncate)
        int ec_n   = (7 + e_lead) & 15;
        int mant_n = (int)(ub >> 20) & 7;
        // subnormal range [2^-10, 2^-6): bits at weights 2^-7..2^-9
        int mant_s = ((int)(a * 512.0f)) & 7;   // a*512 in [0.5, 8), exact scaling, trunc
        ec   = norm ? ec_n : 0;
        mant = norm ? mant_n : (sub ? mant_s : 0);
    }

    lo.x = sign;
    lo.y = (float)((ec >> 3) & 1);   // e_out is e_reg reversed => MSB first
    lo.z = (float)((ec >> 2) & 1);
    lo.w = (float)((ec >> 1) & 1);
    hi.x = (float)(ec & 1);
    hi.y = (float)((mant >> 2) & 1); // m_reg[0] = most significant mantissa bit
    hi.z = (float)((mant >> 1) & 1);
    hi.w = (float)(mant & 1);
}

__device__ __forceinline__ void emit(f32x4* __restrict__ out4, long e, float x) {
    f32x4 lo, hi;
    encode_one(x, lo, hi);
    __builtin_nontemporal_store(lo, &out4[2 * e]);
    __builtin_nontemporal_store(hi, &out4[2 * e + 1]);
}

// 4 grid-strided elements per thread; loads batched for MLP=4.
__global__ __launch_bounds__(256) void pulse_encode_kernel(
        const float* __restrict__ in, f32x4* __restrict__ out4, int n) {
    const int tid = blockIdx.x * 256 + threadIdx.x;
    const int total = gridDim.x * 256;            // n/4 by construction
    const long e0 = tid;
    const long e1 = tid + (long)total;
    const long e2 = tid + 2L * total;
    const long e3 = tid + 3L * total;
    // 4 independent dense loads, all in flight before first use
    float x0 = __builtin_nontemporal_load(&in[e0]);
    float x1 = __builtin_nontemporal_load(&in[e1]);
    float x2 = __builtin_nontemporal_load(&in[e2]);
    float x3 = __builtin_nontemporal_load(&in[e3]);
    emit(out4, e0, x0);
    emit(out4, e1, x1);
    emit(out4, e2, x2);
    emit(out4, e3, x3);
}

extern "C" void kernel_launch(void* const* d_in, const int* in_sizes, int n_in,
                              void* d_out, int out_size, void* d_ws, size_t ws_size,
                              hipStream_t stream) {
    const float* x = (const float*)d_in[0];
    f32x4* out = (f32x4*)d_out;
    int n = in_sizes[0];                  // 8*2048*1024 = 16,777,216 (divisible by 1024)
    int threads_total = n / 4;            // 4,194,304
    int blocks = threads_total / 256;     // 16384
    pulse_encode_kernel<<<blocks, 256, 0, stream>>>(x, out, n);
}